// Round 2
// 102.358 us; speedup vs baseline: 1.0035x; 1.0035x over previous
//
#include <hip/hip_runtime.h>

// TT embedding: cores
//   core0: (1, 8, 40, 16)   [a, x, p, b]
//   core1: (16, 8, 32, 16)  [b, y, q, c]
//   core2: (16, 16, 25, 1)  [c, z, r, d]
// out[t, e] with e = (x*8+y)*16+z, token id v -> p=v/800, q=(v/25)%32, r=v%25
//
// T12 is stored PERMUTED: slab pq, float index c*64 + g*4 + i holds the value
// for xy = i*16 + g  (g in 0..15, i in 0..3). This makes the gather's output
// stores fully contiguous (1 KB per store instruction) while keeping the
// E-loads the same 256B-per-c pattern.
// Output stores are nontemporal so the 64 MiB stream does not evict T12 from L2.

typedef float vfloat4 __attribute__((ext_vector_type(4)));  // native vec for builtins

#define T12_FLOATS (40 * 32 * 16 * 64)
#define C2T_FLOATS (25 * 16 * 16)

__global__ __launch_bounds__(256) void tt_precompute_kernel(
    const float* __restrict__ core0, const float* __restrict__ core1,
    const float* __restrict__ core2, float* __restrict__ T12,
    float* __restrict__ C2T) {
  if (blockIdx.x == 1280) {
    // transpose core2 -> C2T[r*256 + c*16 + z] = core2[(c*16+z)*25 + r]
    for (int i = threadIdx.x; i < C2T_FLOATS; i += 256) {
      int r = i >> 8;        // i / 256
      int cz = i & 255;      // c*16+z
      C2T[i] = core2[cz * 25 + r];
    }
    return;
  }
  int pq = blockIdx.x;  // 0..1279
  int p = pq >> 5;      // / 32
  int q = pq & 31;

  __shared__ float sA[8 * 16];        // core0[x][b] at this p
  __shared__ float sB[16 * 8 * 16];   // core1[b][y][c] at this q

  for (int i = threadIdx.x; i < 128; i += 256) {
    int x = i >> 4, b = i & 15;
    sA[i] = core0[(x * 40 + p) * 16 + b];
  }
  for (int i = threadIdx.x; i < 2048; i += 256) {
    int b = i >> 7;        // / 128
    int yc = i & 127;      // y*16+c
    int y = yc >> 4, c = yc & 15;
    sB[i] = core1[((b * 8 + y) * 32 + q) * 16 + c];
  }
  __syncthreads();

  // 1024 outputs per (p,q); permuted dst offset: g = xy&15, i = xy>>4.
  // Within one c-block the wave still writes one contiguous 256B region
  // (lane-permuted), so stores stay coalesced.
  float* dst = T12 + pq * 1024;
  int xy = threadIdx.x & 63;
  int x = xy >> 3, y = xy & 7;
  int dof = (xy & 15) * 4 + (xy >> 4);
  for (int c = threadIdx.x >> 6; c < 16; c += 4) {
    float acc = 0.f;
#pragma unroll
    for (int b = 0; b < 16; b++) acc += sA[x * 16 + b] * sB[b * 128 + y * 16 + c];
    dst[c * 64 + dof] = acc;
  }
}

__global__ __launch_bounds__(256, 4) void tt_gather_kernel(
    const float* __restrict__ T12, const float* __restrict__ C2T,
    const int* __restrict__ ids, float* __restrict__ out) {
  int wave = threadIdx.x >> 6;
  int lane = threadIdx.x & 63;
  int t = blockIdx.x * 4 + wave;  // token index, grid exactly covers 16384

  int id = ids[t];
  int p = id / 800;
  int rem = id - p * 800;
  int q = rem / 25;
  int r = rem - q * 25;

  const float4* E = (const float4*)(T12 + (p * 32 + q) * 1024);  // [c][g]: float4 over i
  const float4* C = (const float4*)(C2T + r * 256);              // [c][z/4]

  int xyg = lane >> 2;  // g: 0..15
  int zg = lane & 3;    // 0..3 : z in [zg*4, zg*4+4)

  float acc[4][4];
#pragma unroll
  for (int i = 0; i < 4; i++)
#pragma unroll
    for (int j = 0; j < 4; j++) acc[i][j] = 0.f;

  // 4-deep chunked software pipeline over c: 8 loads in flight while the
  // previous chunk's 64 FMAs issue. ~90 VGPRs -> 4 waves/SIMD.
  float4 e[4], w[4];
#pragma unroll
  for (int k = 0; k < 4; k++) {
    e[k] = E[k * 16 + xyg];
    w[k] = C[k * 4 + zg];
  }

#pragma unroll
  for (int cc = 0; cc < 4; cc++) {
    float4 en[4], wn[4];
    if (cc < 3) {
#pragma unroll
      for (int k = 0; k < 4; k++) {
        en[k] = E[((cc + 1) * 4 + k) * 16 + xyg];
        wn[k] = C[((cc + 1) * 4 + k) * 4 + zg];
      }
    }
#pragma unroll
    for (int k = 0; k < 4; k++) {
      float ev[4] = {e[k].x, e[k].y, e[k].z, e[k].w};  // ev[i]: xy = i*16+xyg
      float wv[4] = {w[k].x, w[k].y, w[k].z, w[k].w};  // wv[j]: z  = zg*4+j
#pragma unroll
      for (int i = 0; i < 4; i++)
#pragma unroll
        for (int j = 0; j < 4; j++) acc[i][j] += ev[i] * wv[j];
    }
    if (cc < 3) {
#pragma unroll
      for (int k = 0; k < 4; k++) {
        e[k] = en[k];
        w[k] = wn[k];
      }
    }
  }

  // e = xy*16 + z = i*256 + xyg*16 + zg*4 + j = i*256 + lane*4 + j
  // -> each store instruction writes 1 KB fully contiguous; nontemporal so
  //    the output stream does not thrash L2 (keep T12 resident).
  float* dst = out + (size_t)t * 1024 + lane * 4;
#pragma unroll
  for (int i = 0; i < 4; i++) {
    vfloat4 v = {acc[i][0], acc[i][1], acc[i][2], acc[i][3]};
    __builtin_nontemporal_store(v, (vfloat4*)(dst + i * 256));
  }
}

extern "C" void kernel_launch(void* const* d_in, const int* in_sizes, int n_in,
                              void* d_out, int out_size, void* d_ws, size_t ws_size,
                              hipStream_t stream) {
  const float* core0 = (const float*)d_in[0];
  const float* core1 = (const float*)d_in[1];
  const float* core2 = (const float*)d_in[2];
  const int* ids = (const int*)d_in[3];
  float* out = (float*)d_out;

  float* T12 = (float*)d_ws;
  float* C2T = T12 + T12_FLOATS;  // 5.24 MB + 25.6 KB total in workspace

  tt_precompute_kernel<<<dim3(1281), dim3(256), 0, stream>>>(core0, core1, core2, T12, C2T);
  tt_gather_kernel<<<dim3(16384 / 4), dim3(256), 0, stream>>>(T12, C2T, ids, out);
}